// Round 6
// baseline (281.963 us; speedup 1.0000x reference)
//
#include <hip/hip_runtime.h>
#include <hip/hip_bf16.h>

typedef __attribute__((ext_vector_type(8))) short short8;
typedef __attribute__((ext_vector_type(4))) float f32x4;
typedef __attribute__((ext_vector_type(2))) float f32x2;

#define BUK_SHIFT 7
#define BUK_ROWS 128
#define MAXBUK 400
#define NBLK_BIN 128
#define CAP2 6144     // per-bucket stride (4B elems) in padded edge array

static __device__ __forceinline__ unsigned short f2bf(float f) {
    unsigned u = __float_as_uint(f);
    u += 0x7fffu + ((u >> 16) & 1u);
    return (unsigned short)(u >> 16);
}

__global__ void cvt_kernel(const float* __restrict__ in, unsigned short* __restrict__ out, int n4) {
    int i = blockIdx.x * blockDim.x + threadIdx.x;
    if (i >= n4) return;
    float4 v = reinterpret_cast<const float4*>(in)[i];
    ushort4 o;
    o.x = f2bf(v.x); o.y = f2bf(v.y); o.z = f2bf(v.z); o.w = f2bf(v.w);
    reinterpret_cast<ushort4*>(out)[i] = o;
}

__global__ void wtr_kernel(const float* __restrict__ W, unsigned short* __restrict__ Wt) {
    int k = blockIdx.x, n = threadIdx.x;
    Wt[n * 256 + k] = f2bf(W[k * 256 + n]);
}

// ---- CSR build (two-level binning; natural row order; rows padded to %8; 4B packed edges) ----

__global__ __launch_bounds__(1024) void bin_count(const int* __restrict__ rows,
                                                  int* __restrict__ cntM, int E, int nbuk, int ce) {
    __shared__ int c[MAXBUK];
    for (int i = threadIdx.x; i < nbuk; i += 1024) c[i] = 0;
    __syncthreads();
    int s = blockIdx.x * ce, e = s + ce < E ? s + ce : E;
    for (int i = s + (int)threadIdx.x; i < e; i += 1024) atomicAdd(&c[rows[i] >> BUK_SHIFT], 1);
    __syncthreads();
    for (int i = threadIdx.x; i < nbuk; i += 1024) cntM[i * gridDim.x + blockIdx.x] = c[i];
}

__global__ __launch_bounds__(1024) void scan1_kernel(const int* __restrict__ in,
                                                     int* __restrict__ tmp,
                                                     int* __restrict__ bsum, int n) {
    __shared__ int sdata[1024];
    int i = blockIdx.x * 1024 + threadIdx.x;
    int v = (i < n) ? in[i] : 0;
    sdata[threadIdx.x] = v;
    __syncthreads();
    for (int off = 1; off < 1024; off <<= 1) {
        int t = (threadIdx.x >= (unsigned)off) ? sdata[threadIdx.x - off] : 0;
        __syncthreads();
        sdata[threadIdx.x] += t;
        __syncthreads();
    }
    if (i < n) tmp[i] = sdata[threadIdx.x] - v;
    if (threadIdx.x == 1023) bsum[blockIdx.x] = sdata[1023];
}

__global__ void scan2_kernel(const int* __restrict__ bsum, int* __restrict__ boff, int nb) {
    __shared__ int s[64];
    int t = threadIdx.x;
    int v = (t < nb) ? bsum[t] : 0;
    s[t] = v;
    __syncthreads();
    for (int off = 1; off < 64; off <<= 1) {
        int x = (t >= off) ? s[t - off] : 0;
        __syncthreads();
        s[t] += x;
        __syncthreads();
    }
    boff[t] = s[t] - v;
}

__global__ void scan3_kernel(const int* __restrict__ tmp, const int* __restrict__ boff,
                             int* __restrict__ out, int n) {
    int i = blockIdx.x * blockDim.x + threadIdx.x;
    if (i < n) out[i] = tmp[i] + boff[i >> 10];
}

__global__ __launch_bounds__(1024) void bin_scatter(const int* __restrict__ rows,
                                                    const int* __restrict__ cols,
                                                    const float* __restrict__ vals,
                                                    const int* __restrict__ cntS,
                                                    unsigned int* __restrict__ cc,
                                                    unsigned char* __restrict__ rb,
                                                    int E, int nbuk, int ce) {
    __shared__ int cur[MAXBUK];
    for (int i = threadIdx.x; i < nbuk; i += 1024) cur[i] = cntS[i * gridDim.x + blockIdx.x];
    __syncthreads();
    int s = blockIdx.x * ce, e = s + ce < E ? s + ce : E;
    for (int i = s + (int)threadIdx.x; i < e; i += 1024) {
        int r = rows[i];
        int p = atomicAdd(&cur[r >> BUK_SHIFT], 1);
        cc[p] = ((unsigned)cols[i] << 16) | (unsigned)f2bf(vals[i]);
        rb[p] = (unsigned char)(r & (BUK_ROWS - 1));
    }
}

// per-bucket: natural row order, pad each row to %8 with 0 (col=0,val=0); emit rp; write cc2
__global__ __launch_bounds__(1024) void bucket_pad(const unsigned int* __restrict__ cc,
                                                   const unsigned char* __restrict__ rb,
                                                   const int* __restrict__ cntS,
                                                   unsigned int* __restrict__ cc2,
                                                   int2* __restrict__ rp,
                                                   int E, int nbuk, int nblk, int N) {
    __shared__ int cnt[BUK_ROWS];
    __shared__ int psc[BUK_ROWS];
    __shared__ int cur[BUK_ROWS];
    const int b = blockIdx.x;
    const int tid = threadIdx.x;
    const int base = cntS[b * nblk];
    const int end = (b + 1 < nbuk) ? cntS[(b + 1) * nblk] : E;
    const int sz = end - base;
    if (tid < BUK_ROWS) cnt[tid] = 0;
    __syncthreads();
    for (int i = tid; i < sz; i += 1024) atomicAdd(&cnt[rb[base + i]], 1);
    __syncthreads();
    if (tid < BUK_ROWS) psc[tid] = (cnt[tid] + 7) & ~7;
    __syncthreads();
    for (int off = 1; off < BUK_ROWS; off <<= 1) {
        int t = (tid < BUK_ROWS && tid >= off) ? psc[tid - off] : 0;
        __syncthreads();
        if (tid < BUK_ROWS) psc[tid] += t;
        __syncthreads();
    }
    if (tid < BUK_ROWS) {
        int c = cnt[tid];
        int pc = (c + 7) & ~7;
        int excl = psc[tid] - pc;
        cur[tid] = excl;
        int st = b * CAP2 + excl;
        rp[b * BUK_ROWS + tid] = make_int2(st, st + pc);
        for (int z = c; z < pc; ++z) cc2[(size_t)st + z] = 0u;  // pad slots
    }
    __syncthreads();
    for (int i = tid; i < sz; i += 1024) {
        int p = atomicAdd(&cur[rb[base + i]], 1);
        cc2[(size_t)b * CAP2 + p] = cc[base + i];
    }
}

// S8 slabs [4][N][64] fp8 e4m3 = fp8(A[m][256] @ Bt[n][256]^T), bf16 in, f32 accum.
// transposed-operand MFMA: mfma(b,a) -> D[n via reg][m via lane&15]; lane holds 4
// consecutive features of one node -> in-register fp8 pack, one dword store.
__global__ __launch_bounds__(256) void gemm_kernel(const unsigned short* __restrict__ A,
                                                   const unsigned short* __restrict__ Bt,
                                                   unsigned char* __restrict__ S8, int M) {
    const int lane = threadIdx.x & 63;
    const int wave = threadIdx.x >> 6;
    const int m0 = blockIdx.x * 64;
    const int n0 = wave * 64;
    const int l15 = lane & 15;
    const int lk = (lane >> 4) * 8;
    f32x4 acc[4][4] = {};
    const unsigned short* aptr[4];
    const unsigned short* bptr[4];
#pragma unroll
    for (int mf = 0; mf < 4; ++mf) {
        int row = m0 + mf * 16 + l15;
        aptr[mf] = A + (size_t)(row < M ? row : 0) * 256 + lk;
    }
#pragma unroll
    for (int nf = 0; nf < 4; ++nf) bptr[nf] = Bt + (size_t)(n0 + nf * 16 + l15) * 256 + lk;
    for (int kk = 0; kk < 256; kk += 32) {
        short8 a[4], b[4];
#pragma unroll
        for (int mf = 0; mf < 4; ++mf) a[mf] = *reinterpret_cast<const short8*>(aptr[mf] + kk);
#pragma unroll
        for (int nf = 0; nf < 4; ++nf) b[nf] = *reinterpret_cast<const short8*>(bptr[nf] + kk);
#pragma unroll
        for (int mf = 0; mf < 4; ++mf)
#pragma unroll
            for (int nf = 0; nf < 4; ++nf)
                acc[mf][nf] = __builtin_amdgcn_mfma_f32_16x16x32_bf16(b[nf], a[mf], acc[mf][nf], 0, 0, 0);
    }
    const int g4 = (lane >> 4) * 4;
#pragma unroll
    for (int mf = 0; mf < 4; ++mf) {
        int m = m0 + mf * 16 + l15;
        if (m < M) {
#pragma unroll
            for (int nf = 0; nf < 4; ++nf) {
                int p = __builtin_amdgcn_cvt_pk_fp8_f32(acc[mf][nf][0], acc[mf][nf][1], 0, false);
                p = __builtin_amdgcn_cvt_pk_fp8_f32(acc[mf][nf][2], acc[mf][nf][3], p, true);
                // slab = wave (features n0..n0+63); within-slab feat = nf*16+g4
                *reinterpret_cast<int*>(S8 + ((size_t)wave * M + m) * 64 + nf * 16 + g4) = p;
            }
        }
    }
}

// SpMM pass over one 64-feature slab: wave = 4 rows x 16 lanes; lane owns 4 feats (dword gather)
template <int LAYER2>
__global__ __launch_bounds__(256) void spmm_kernel(const unsigned char* __restrict__ S8,
                                                   const int2* __restrict__ rp,
                                                   const unsigned int* __restrict__ cc,
                                                   const float* __restrict__ bias,
                                                   unsigned short* __restrict__ out_bf,
                                                   float* __restrict__ out_f,
                                                   const int* __restrict__ pos_idx,
                                                   int N, int slab) {
    const int lane = threadIdx.x & 63;
    const int wid = threadIdx.x >> 6;
    const int q = lane >> 4;
    const int l = lane & 15;
    const int row = blockIdx.x * 16 + wid * 4 + q;
    const int2 r = rp[row];
    float a0 = 0.f, a1 = 0.f, a2 = 0.f, a3 = 0.f;
    const unsigned char* Sl = S8 + (size_t)slab * N * 64 + l * 4;
    for (int i = r.x; i < r.y; i += 8) {
        uint4 c0 = *reinterpret_cast<const uint4*>(cc + i);
        uint4 c1 = *reinterpret_cast<const uint4*>(cc + i + 4);
        unsigned w0 = *reinterpret_cast<const unsigned*>(Sl + ((size_t)(c0.x >> 16) << 6));
        unsigned w1 = *reinterpret_cast<const unsigned*>(Sl + ((size_t)(c0.y >> 16) << 6));
        unsigned w2 = *reinterpret_cast<const unsigned*>(Sl + ((size_t)(c0.z >> 16) << 6));
        unsigned w3 = *reinterpret_cast<const unsigned*>(Sl + ((size_t)(c0.w >> 16) << 6));
        unsigned w4 = *reinterpret_cast<const unsigned*>(Sl + ((size_t)(c1.x >> 16) << 6));
        unsigned w5 = *reinterpret_cast<const unsigned*>(Sl + ((size_t)(c1.y >> 16) << 6));
        unsigned w6 = *reinterpret_cast<const unsigned*>(Sl + ((size_t)(c1.z >> 16) << 6));
        unsigned w7 = *reinterpret_cast<const unsigned*>(Sl + ((size_t)(c1.w >> 16) << 6));
        float v0 = __uint_as_float(c0.x << 16), v1 = __uint_as_float(c0.y << 16);
        float v2 = __uint_as_float(c0.z << 16), v3 = __uint_as_float(c0.w << 16);
        float v4 = __uint_as_float(c1.x << 16), v5 = __uint_as_float(c1.y << 16);
        float v6 = __uint_as_float(c1.z << 16), v7 = __uint_as_float(c1.w << 16);
#define ACC(ww, vv) { \
        f32x2 plo = __builtin_amdgcn_cvt_pk_f32_fp8((int)ww, false); \
        f32x2 phi = __builtin_amdgcn_cvt_pk_f32_fp8((int)ww, true);  \
        a0 += vv * plo.x; a1 += vv * plo.y; a2 += vv * phi.x; a3 += vv * phi.y; }
        ACC(w0, v0) ACC(w1, v1) ACC(w2, v2) ACC(w3, v3)
        ACC(w4, v4) ACC(w5, v5) ACC(w6, v6) ACC(w7, v7)
#undef ACC
    }
    if (row >= N) return;
    const int f = slab * 64 + l * 4;
    a0 = fmaxf(a0 + bias[f + 0], 0.f);
    a1 = fmaxf(a1 + bias[f + 1], 0.f);
    a2 = fmaxf(a2 + bias[f + 2], 0.f);
    a3 = fmaxf(a3 + bias[f + 3], 0.f);
    if (LAYER2) {
        int orow = pos_idx[row];
        *reinterpret_cast<float4*>(out_f + (size_t)orow * 256 + f) = make_float4(a0, a1, a2, a3);
    } else {
        ushort4 o;
        o.x = f2bf(a0); o.y = f2bf(a1); o.z = f2bf(a2); o.w = f2bf(a3);
        *reinterpret_cast<ushort4*>(out_bf + (size_t)row * 256 + f) = o;
    }
}

extern "C" void kernel_launch(void* const* d_in, const int* in_sizes, int n_in,
                              void* d_out, int out_size, void* d_ws, size_t ws_size,
                              hipStream_t stream) {
    const float* x        = (const float*)d_in[0];
    const int* adj_rows   = (const int*)d_in[1];
    const int* adj_cols   = (const int*)d_in[2];
    const float* adj_vals = (const float*)d_in[3];
    const int* pos_idx    = (const int*)d_in[5];
    const float* W1       = (const float*)d_in[6];
    const float* b1       = (const float*)d_in[7];
    const float* W2       = (const float*)d_in[8];
    const float* b2       = (const float*)d_in[9];

    const int N = in_sizes[0] / 256;
    const int E = in_sizes[1];
    const int nbuk = (N + BUK_ROWS - 1) >> BUK_SHIFT;       // 391
    const int n2 = nbuk * NBLK_BIN;
    const int nb2 = (n2 + 1023) / 1024;
    const int ce = (E + NBLK_BIN - 1) / NBLK_BIN;
    const int nwork = nbuk * BUK_ROWS;                      // 50048

    char* ws = (char*)d_ws;
    size_t off = 0;
    auto alloc = [&](size_t bytes) {
        char* p = ws + off;
        off += (bytes + 255) & ~(size_t)255;
        return p;
    };
    unsigned short* xb   = (unsigned short*)alloc((size_t)N * 256 * 2); // x bf16, reused as h
    unsigned char*  sup8 = (unsigned char*)alloc((size_t)N * 256);      // fp8 support, slab layout
    unsigned short* w1t  = (unsigned short*)alloc(256 * 256 * 2);
    unsigned short* w2t  = (unsigned short*)alloc(256 * 256 * 2);
    int2* rp     = (int2*)alloc((size_t)nwork * 8);
    int* cntM    = (int*)alloc((size_t)n2 * 4);
    int* cntS    = (int*)alloc((size_t)n2 * 4);
    int* tmp     = (int*)alloc((size_t)n2 * 4);
    int* bsum    = (int*)alloc(64 * 4);
    int* boff    = (int*)alloc(64 * 4);
    unsigned int* cc  = (unsigned int*)alloc((size_t)E * 4);
    unsigned char* rb = (unsigned char*)alloc((size_t)E);
    unsigned int* cc2 = (unsigned int*)alloc((size_t)nbuk * CAP2 * 4);
    (void)ws_size; (void)n_in;

    // only rows [N, PAD_N) need zeroing: spmm layer-2 writes all rows pos_idx[0..N) fully
    hipMemsetAsync((float*)d_out + (size_t)N * 256, 0,
                   ((size_t)out_size - (size_t)N * 256) * 4, stream);

    cvt_kernel<<<(N * 64 + 255) / 256, 256, 0, stream>>>(x, xb, N * 64);
    wtr_kernel<<<256, 256, 0, stream>>>(W1, w1t);
    wtr_kernel<<<256, 256, 0, stream>>>(W2, w2t);

    // CSR build (natural order, padded, 4B packed)
    bin_count<<<NBLK_BIN, 1024, 0, stream>>>(adj_rows, cntM, E, nbuk, ce);
    scan1_kernel<<<nb2, 1024, 0, stream>>>(cntM, tmp, bsum, n2);
    scan2_kernel<<<1, 64, 0, stream>>>(bsum, boff, nb2);
    scan3_kernel<<<(n2 + 255) / 256, 256, 0, stream>>>(tmp, boff, cntS, n2);
    bin_scatter<<<NBLK_BIN, 1024, 0, stream>>>(adj_rows, adj_cols, adj_vals, cntS, cc, rb, E, nbuk, ce);
    bucket_pad<<<nbuk, 1024, 0, stream>>>(cc, rb, cntS, cc2, rp, E, nbuk, NBLK_BIN, N);

    const int ggrid = (N + 63) / 64;
    const int sgrid = nwork / 16;
    // layer 1
    gemm_kernel<<<ggrid, 256, 0, stream>>>(xb, w1t, sup8, N);
    for (int s = 0; s < 4; ++s)
        spmm_kernel<0><<<sgrid, 256, 0, stream>>>(sup8, rp, cc2, b1, xb, nullptr, nullptr, N, s);
    // layer 2
    gemm_kernel<<<ggrid, 256, 0, stream>>>(xb, w2t, sup8, N);
    for (int s = 0; s < 4; ++s)
        spmm_kernel<1><<<sgrid, 256, 0, stream>>>(sup8, rp, cc2, b2, nullptr, (float*)d_out, pos_idx, N, s);
}

// Round 7
// 266.399 us; speedup vs baseline: 1.0584x; 1.0584x over previous
//
#include <hip/hip_runtime.h>
#include <hip/hip_bf16.h>

typedef __attribute__((ext_vector_type(8))) short short8;
typedef __attribute__((ext_vector_type(4))) float f32x4;
typedef __attribute__((ext_vector_type(2))) float f32x2;

#define BUK_SHIFT 7
#define BUK_ROWS 128
#define MAXBUK 400
#define NBLK_BIN 1024
#define CAP2 6144     // per-bucket stride (4B elems) in padded edge array

static __device__ __forceinline__ unsigned short f2bf(float f) {
    unsigned u = __float_as_uint(f);
    u += 0x7fffu + ((u >> 16) & 1u);
    return (unsigned short)(u >> 16);
}

__global__ void wtr_kernel(const float* __restrict__ W, unsigned short* __restrict__ Wt) {
    int k = blockIdx.x, n = threadIdx.x;
    Wt[n * 256 + k] = f2bf(W[k * 256 + n]);
}

// ---- CSR build (two-level binning; natural row order; rows padded to %8; 4B packed edges) ----

__global__ __launch_bounds__(256) void bin_count(const int* __restrict__ rows,
                                                 int* __restrict__ cntM, int E, int nbuk, int ce) {
    __shared__ int c[MAXBUK];
    for (int i = threadIdx.x; i < nbuk; i += 256) c[i] = 0;
    __syncthreads();
    int s = blockIdx.x * ce, e = s + ce < E ? s + ce : E;
    for (int i = s + (int)threadIdx.x; i < e; i += 256) atomicAdd(&c[rows[i] >> BUK_SHIFT], 1);
    __syncthreads();
    for (int i = threadIdx.x; i < nbuk; i += 256) cntM[i * gridDim.x + blockIdx.x] = c[i];
}

__global__ __launch_bounds__(1024) void scan1_kernel(const int* __restrict__ in,
                                                     int* __restrict__ tmp,
                                                     int* __restrict__ bsum, int n) {
    __shared__ int sdata[1024];
    int i = blockIdx.x * 1024 + threadIdx.x;
    int v = (i < n) ? in[i] : 0;
    sdata[threadIdx.x] = v;
    __syncthreads();
    for (int off = 1; off < 1024; off <<= 1) {
        int t = (threadIdx.x >= (unsigned)off) ? sdata[threadIdx.x - off] : 0;
        __syncthreads();
        sdata[threadIdx.x] += t;
        __syncthreads();
    }
    if (i < n) tmp[i] = sdata[threadIdx.x] - v;
    if (threadIdx.x == 1023) bsum[blockIdx.x] = sdata[1023];
}

// single block scans up to 512 block sums
__global__ __launch_bounds__(512) void scan2_kernel(const int* __restrict__ bsum,
                                                    int* __restrict__ boff, int nb) {
    __shared__ int s[512];
    int t = threadIdx.x;
    int v = (t < nb) ? bsum[t] : 0;
    s[t] = v;
    __syncthreads();
    for (int off = 1; off < 512; off <<= 1) {
        int x = (t >= off) ? s[t - off] : 0;
        __syncthreads();
        s[t] += x;
        __syncthreads();
    }
    if (t < nb) boff[t] = s[t] - v;
}

__global__ void scan3_kernel(const int* __restrict__ tmp, const int* __restrict__ boff,
                             int* __restrict__ out, int n) {
    int i = blockIdx.x * blockDim.x + threadIdx.x;
    if (i < n) out[i] = tmp[i] + boff[i >> 10];
}

__global__ __launch_bounds__(256) void bin_scatter(const int* __restrict__ rows,
                                                   const int* __restrict__ cols,
                                                   const float* __restrict__ vals,
                                                   const int* __restrict__ cntS,
                                                   unsigned int* __restrict__ cc,
                                                   unsigned char* __restrict__ rb,
                                                   int E, int nbuk, int ce) {
    __shared__ int cur[MAXBUK];
    for (int i = threadIdx.x; i < nbuk; i += 256) cur[i] = cntS[i * gridDim.x + blockIdx.x];
    __syncthreads();
    int s = blockIdx.x * ce, e = s + ce < E ? s + ce : E;
    for (int i = s + (int)threadIdx.x; i < e; i += 256) {
        int r = rows[i];
        int p = atomicAdd(&cur[r >> BUK_SHIFT], 1);
        cc[p] = ((unsigned)cols[i] << 16) | (unsigned)f2bf(vals[i]);
        rb[p] = (unsigned char)(r & (BUK_ROWS - 1));
    }
}

// per-bucket: natural row order, pad each row to %8 with 0 (col=0,val=0); emit rp; write cc2
__global__ __launch_bounds__(1024) void bucket_pad(const unsigned int* __restrict__ cc,
                                                   const unsigned char* __restrict__ rb,
                                                   const int* __restrict__ cntS,
                                                   unsigned int* __restrict__ cc2,
                                                   int2* __restrict__ rp,
                                                   int E, int nbuk, int nblk, int N) {
    __shared__ int cnt[BUK_ROWS];
    __shared__ int psc[BUK_ROWS];
    __shared__ int cur[BUK_ROWS];
    const int b = blockIdx.x;
    const int tid = threadIdx.x;
    const int base = cntS[b * nblk];
    const int end = (b + 1 < nbuk) ? cntS[(b + 1) * nblk] : E;
    const int sz = end - base;
    if (tid < BUK_ROWS) cnt[tid] = 0;
    __syncthreads();
    for (int i = tid; i < sz; i += 1024) atomicAdd(&cnt[rb[base + i]], 1);
    __syncthreads();
    if (tid < BUK_ROWS) psc[tid] = (cnt[tid] + 7) & ~7;
    __syncthreads();
    for (int off = 1; off < BUK_ROWS; off <<= 1) {
        int t = (tid < BUK_ROWS && tid >= off) ? psc[tid - off] : 0;
        __syncthreads();
        if (tid < BUK_ROWS) psc[tid] += t;
        __syncthreads();
    }
    if (tid < BUK_ROWS) {
        int c = cnt[tid];
        int pc = (c + 7) & ~7;
        int excl = psc[tid] - pc;
        cur[tid] = excl;
        int st = b * CAP2 + excl;
        rp[b * BUK_ROWS + tid] = make_int2(st, st + pc);
        for (int z = c; z < pc; ++z) cc2[(size_t)st + z] = 0u;  // pad slots
    }
    __syncthreads();
    for (int i = tid; i < sz; i += 1024) {
        int p = atomicAdd(&cur[rb[base + i]], 1);
        cc2[(size_t)b * CAP2 + p] = cc[base + i];
    }
}

// S8 slabs [4][N][64] fp8 e4m3 = fp8(A[m][256] @ Bt[n][256]^T), f32 accum.
// AF32: A is f32 (layer 1 reads x directly, packs bf16 in-register); else A is bf16.
// transposed-operand MFMA: mfma(b,a) -> D[n via reg][m via lane&15]; lane holds 4
// consecutive features of one node -> in-register fp8 pack, one dword store.
template <int AF32>
__global__ __launch_bounds__(256) void gemm_kernel(const void* __restrict__ Av,
                                                   const unsigned short* __restrict__ Bt,
                                                   unsigned char* __restrict__ S8, int M) {
    const int lane = threadIdx.x & 63;
    const int wave = threadIdx.x >> 6;
    const int m0 = blockIdx.x * 64;
    const int n0 = wave * 64;
    const int l15 = lane & 15;
    const int lk = (lane >> 4) * 8;
    f32x4 acc[4][4] = {};
    const unsigned short* aptr[4];
    const float* aptrf[4];
    const unsigned short* bptr[4];
#pragma unroll
    for (int mf = 0; mf < 4; ++mf) {
        int row = m0 + mf * 16 + l15;
        row = row < M ? row : 0;
        if (AF32) aptrf[mf] = (const float*)Av + (size_t)row * 256 + lk;
        else      aptr[mf]  = (const unsigned short*)Av + (size_t)row * 256 + lk;
    }
#pragma unroll
    for (int nf = 0; nf < 4; ++nf) bptr[nf] = Bt + (size_t)(n0 + nf * 16 + l15) * 256 + lk;
    for (int kk = 0; kk < 256; kk += 32) {
        short8 a[4], b[4];
#pragma unroll
        for (int mf = 0; mf < 4; ++mf) {
            if (AF32) {
                float4 f0 = *reinterpret_cast<const float4*>(aptrf[mf] + kk);
                float4 f1 = *reinterpret_cast<const float4*>(aptrf[mf] + kk + 4);
                short8 t;
                t[0] = (short)f2bf(f0.x); t[1] = (short)f2bf(f0.y);
                t[2] = (short)f2bf(f0.z); t[3] = (short)f2bf(f0.w);
                t[4] = (short)f2bf(f1.x); t[5] = (short)f2bf(f1.y);
                t[6] = (short)f2bf(f1.z); t[7] = (short)f2bf(f1.w);
                a[mf] = t;
            } else {
                a[mf] = *reinterpret_cast<const short8*>(aptr[mf] + kk);
            }
        }
#pragma unroll
        for (int nf = 0; nf < 4; ++nf) b[nf] = *reinterpret_cast<const short8*>(bptr[nf] + kk);
#pragma unroll
        for (int mf = 0; mf < 4; ++mf)
#pragma unroll
            for (int nf = 0; nf < 4; ++nf)
                acc[mf][nf] = __builtin_amdgcn_mfma_f32_16x16x32_bf16(b[nf], a[mf], acc[mf][nf], 0, 0, 0);
    }
    const int g4 = (lane >> 4) * 4;
#pragma unroll
    for (int mf = 0; mf < 4; ++mf) {
        int m = m0 + mf * 16 + l15;
        if (m < M) {
#pragma unroll
            for (int nf = 0; nf < 4; ++nf) {
                int p = __builtin_amdgcn_cvt_pk_fp8_f32(acc[mf][nf][0], acc[mf][nf][1], 0, false);
                p = __builtin_amdgcn_cvt_pk_fp8_f32(acc[mf][nf][2], acc[mf][nf][3], p, true);
                // slab = wave (features n0..n0+63); within-slab feat = nf*16+g4
                *reinterpret_cast<int*>(S8 + ((size_t)wave * M + m) * 64 + nf * 16 + g4) = p;
            }
        }
    }
}

// SpMM over one 64-feature slab (blockIdx.y): wave = 4 rows x 16 lanes; lane owns 4 feats
template <int LAYER2>
__global__ __launch_bounds__(256) void spmm_kernel(const unsigned char* __restrict__ S8,
                                                   const int2* __restrict__ rp,
                                                   const unsigned int* __restrict__ cc,
                                                   const float* __restrict__ bias,
                                                   unsigned short* __restrict__ out_bf,
                                                   float* __restrict__ out_f,
                                                   const int* __restrict__ pos_idx, int N) {
    const int slab = blockIdx.y;
    const int lane = threadIdx.x & 63;
    const int wid = threadIdx.x >> 6;
    const int q = lane >> 4;
    const int l = lane & 15;
    const int row = blockIdx.x * 16 + wid * 4 + q;
    const int2 r = rp[row];
    float a0 = 0.f, a1 = 0.f, a2 = 0.f, a3 = 0.f;
    const unsigned char* Sl = S8 + (size_t)slab * N * 64 + l * 4;
    for (int i = r.x; i < r.y; i += 8) {
        uint4 c0 = *reinterpret_cast<const uint4*>(cc + i);
        uint4 c1 = *reinterpret_cast<const uint4*>(cc + i + 4);
        unsigned w0 = *reinterpret_cast<const unsigned*>(Sl + ((size_t)(c0.x >> 16) << 6));
        unsigned w1 = *reinterpret_cast<const unsigned*>(Sl + ((size_t)(c0.y >> 16) << 6));
        unsigned w2 = *reinterpret_cast<const unsigned*>(Sl + ((size_t)(c0.z >> 16) << 6));
        unsigned w3 = *reinterpret_cast<const unsigned*>(Sl + ((size_t)(c0.w >> 16) << 6));
        unsigned w4 = *reinterpret_cast<const unsigned*>(Sl + ((size_t)(c1.x >> 16) << 6));
        unsigned w5 = *reinterpret_cast<const unsigned*>(Sl + ((size_t)(c1.y >> 16) << 6));
        unsigned w6 = *reinterpret_cast<const unsigned*>(Sl + ((size_t)(c1.z >> 16) << 6));
        unsigned w7 = *reinterpret_cast<const unsigned*>(Sl + ((size_t)(c1.w >> 16) << 6));
        float v0 = __uint_as_float(c0.x << 16), v1 = __uint_as_float(c0.y << 16);
        float v2 = __uint_as_float(c0.z << 16), v3 = __uint_as_float(c0.w << 16);
        float v4 = __uint_as_float(c1.x << 16), v5 = __uint_as_float(c1.y << 16);
        float v6 = __uint_as_float(c1.z << 16), v7 = __uint_as_float(c1.w << 16);
#define ACC(ww, vv) { \
        f32x2 plo = __builtin_amdgcn_cvt_pk_f32_fp8((int)ww, false); \
        f32x2 phi = __builtin_amdgcn_cvt_pk_f32_fp8((int)ww, true);  \
        a0 += vv * plo.x; a1 += vv * plo.y; a2 += vv * phi.x; a3 += vv * phi.y; }
        ACC(w0, v0) ACC(w1, v1) ACC(w2, v2) ACC(w3, v3)
        ACC(w4, v4) ACC(w5, v5) ACC(w6, v6) ACC(w7, v7)
#undef ACC
    }
    if (row >= N) return;
    const int f = slab * 64 + l * 4;
    a0 = fmaxf(a0 + bias[f + 0], 0.f);
    a1 = fmaxf(a1 + bias[f + 1], 0.f);
    a2 = fmaxf(a2 + bias[f + 2], 0.f);
    a3 = fmaxf(a3 + bias[f + 3], 0.f);
    if (LAYER2) {
        int orow = pos_idx[row];
        *reinterpret_cast<float4*>(out_f + (size_t)orow * 256 + f) = make_float4(a0, a1, a2, a3);
    } else {
        ushort4 o;
        o.x = f2bf(a0); o.y = f2bf(a1); o.z = f2bf(a2); o.w = f2bf(a3);
        *reinterpret_cast<ushort4*>(out_bf + (size_t)row * 256 + f) = o;
    }
}

extern "C" void kernel_launch(void* const* d_in, const int* in_sizes, int n_in,
                              void* d_out, int out_size, void* d_ws, size_t ws_size,
                              hipStream_t stream) {
    const float* x        = (const float*)d_in[0];
    const int* adj_rows   = (const int*)d_in[1];
    const int* adj_cols   = (const int*)d_in[2];
    const float* adj_vals = (const float*)d_in[3];
    const int* pos_idx    = (const int*)d_in[5];
    const float* W1       = (const float*)d_in[6];
    const float* b1       = (const float*)d_in[7];
    const float* W2       = (const float*)d_in[8];
    const float* b2       = (const float*)d_in[9];

    const int N = in_sizes[0] / 256;
    const int E = in_sizes[1];
    const int nbuk = (N + BUK_ROWS - 1) >> BUK_SHIFT;       // 391
    const int n2 = nbuk * NBLK_BIN;                         // 400384
    const int nb2 = (n2 + 1023) / 1024;                     // 391
    const int ce = (E + NBLK_BIN - 1) / NBLK_BIN;           // 1563
    const int nwork = nbuk * BUK_ROWS;                      // 50048

    char* ws = (char*)d_ws;
    size_t off = 0;
    auto alloc = [&](size_t bytes) {
        char* p = ws + off;
        off += (bytes + 255) & ~(size_t)255;
        return p;
    };
    unsigned short* xb   = (unsigned short*)alloc((size_t)N * 256 * 2); // h (bf16) after layer 1
    unsigned char*  sup8 = (unsigned char*)alloc((size_t)N * 256);      // fp8 support, slab layout
    unsigned short* w1t  = (unsigned short*)alloc(256 * 256 * 2);
    unsigned short* w2t  = (unsigned short*)alloc(256 * 256 * 2);
    int2* rp     = (int2*)alloc((size_t)nwork * 8);
    int* cntM    = (int*)alloc((size_t)n2 * 4);
    int* cntS    = (int*)alloc((size_t)n2 * 4);
    int* tmp     = (int*)alloc((size_t)n2 * 4);
    int* bsum    = (int*)alloc(512 * 4);
    int* boff    = (int*)alloc(512 * 4);
    unsigned int* cc  = (unsigned int*)alloc((size_t)E * 4);
    unsigned char* rb = (unsigned char*)alloc((size_t)E);
    unsigned int* cc2 = (unsigned int*)alloc((size_t)nbuk * CAP2 * 4);
    (void)ws_size; (void)n_in;

    // only rows [N, PAD_N) need zeroing: spmm layer-2 writes all rows pos_idx[0..N) fully
    hipMemsetAsync((float*)d_out + (size_t)N * 256, 0,
                   ((size_t)out_size - (size_t)N * 256) * 4, stream);

    wtr_kernel<<<256, 256, 0, stream>>>(W1, w1t);
    wtr_kernel<<<256, 256, 0, stream>>>(W2, w2t);

    // CSR build (natural order, padded, 4B packed)
    bin_count<<<NBLK_BIN, 256, 0, stream>>>(adj_rows, cntM, E, nbuk, ce);
    scan1_kernel<<<nb2, 1024, 0, stream>>>(cntM, tmp, bsum, n2);
    scan2_kernel<<<1, 512, 0, stream>>>(bsum, boff, nb2);
    scan3_kernel<<<(n2 + 255) / 256, 256, 0, stream>>>(tmp, boff, cntS, n2);
    bin_scatter<<<NBLK_BIN, 256, 0, stream>>>(adj_rows, adj_cols, adj_vals, cntS, cc, rb, E, nbuk, ce);
    bucket_pad<<<nbuk, 1024, 0, stream>>>(cc, rb, cntS, cc2, rp, E, nbuk, NBLK_BIN, N);

    const int ggrid = (N + 63) / 64;
    const dim3 sgrid(nwork / 16, 4);
    // layer 1 (A = x in f32, fused convert)
    gemm_kernel<1><<<ggrid, 256, 0, stream>>>(x, w1t, sup8, N);
    spmm_kernel<0><<<sgrid, 256, 0, stream>>>(sup8, rp, cc2, b1, xb, nullptr, nullptr, N);
    // layer 2 (A = h in bf16)
    gemm_kernel<0><<<ggrid, 256, 0, stream>>>(xb, w2t, sup8, N);
    spmm_kernel<1><<<sgrid, 256, 0, stream>>>(sup8, rp, cc2, b2, nullptr, (float*)d_out, pos_idx, N);
}

// Round 8
// 231.131 us; speedup vs baseline: 1.2199x; 1.1526x over previous
//
#include <hip/hip_runtime.h>
#include <hip/hip_bf16.h>

typedef __attribute__((ext_vector_type(8))) short short8;
typedef __attribute__((ext_vector_type(4))) float f32x4;
typedef __attribute__((ext_vector_type(2))) float f32x2;

#define BUK_SHIFT 7
#define BUK_ROWS 128
#define MAXBUK 400
#define NBLK_BIN 256
#define CAP2 6144     // per-bucket stride (4B elems) in padded edge array

static __device__ __forceinline__ unsigned short f2bf(float f) {
    unsigned u = __float_as_uint(f);
    u += 0x7fffu + ((u >> 16) & 1u);
    return (unsigned short)(u >> 16);
}

// f32 -> bf16, 4 elems/thread
__global__ void cvt_kernel(const float* __restrict__ in, unsigned short* __restrict__ out, int n4) {
    int i = blockIdx.x * blockDim.x + threadIdx.x;
    if (i >= n4) return;
    float4 v = reinterpret_cast<const float4*>(in)[i];
    ushort4 o;
    o.x = f2bf(v.x); o.y = f2bf(v.y); o.z = f2bf(v.z); o.w = f2bf(v.w);
    reinterpret_cast<ushort4*>(out)[i] = o;
}

__global__ void wtr_kernel(const float* __restrict__ W, unsigned short* __restrict__ Wt) {
    int k = blockIdx.x, n = threadIdx.x;
    Wt[n * 256 + k] = f2bf(W[k * 256 + n]);
}

// ---- CSR build (two-level binning; natural row order; rows padded to %8; 4B packed edges) ----

__global__ __launch_bounds__(1024) void bin_count(const int* __restrict__ rows,
                                                  int* __restrict__ cntM, int E, int nbuk, int ce) {
    __shared__ int c[MAXBUK];
    for (int i = threadIdx.x; i < nbuk; i += 1024) c[i] = 0;
    __syncthreads();
    int s = blockIdx.x * ce, e = s + ce < E ? s + ce : E;
    for (int i = s + (int)threadIdx.x; i < e; i += 1024) atomicAdd(&c[rows[i] >> BUK_SHIFT], 1);
    __syncthreads();
    for (int i = threadIdx.x; i < nbuk; i += 1024) cntM[i * gridDim.x + blockIdx.x] = c[i];
}

__global__ __launch_bounds__(1024) void scan1_kernel(const int* __restrict__ in,
                                                     int* __restrict__ tmp,
                                                     int* __restrict__ bsum, int n) {
    __shared__ int sdata[1024];
    int i = blockIdx.x * 1024 + threadIdx.x;
    int v = (i < n) ? in[i] : 0;
    sdata[threadIdx.x] = v;
    __syncthreads();
    for (int off = 1; off < 1024; off <<= 1) {
        int t = (threadIdx.x >= (unsigned)off) ? sdata[threadIdx.x - off] : 0;
        __syncthreads();
        sdata[threadIdx.x] += t;
        __syncthreads();
    }
    if (i < n) tmp[i] = sdata[threadIdx.x] - v;
    if (threadIdx.x == 1023) bsum[blockIdx.x] = sdata[1023];
}

// single block scans up to 512 block sums
__global__ __launch_bounds__(512) void scan2_kernel(const int* __restrict__ bsum,
                                                    int* __restrict__ boff, int nb) {
    __shared__ int s[512];
    int t = threadIdx.x;
    int v = (t < nb) ? bsum[t] : 0;
    s[t] = v;
    __syncthreads();
    for (int off = 1; off < 512; off <<= 1) {
        int x = (t >= off) ? s[t - off] : 0;
        __syncthreads();
        s[t] += x;
        __syncthreads();
    }
    if (t < nb) boff[t] = s[t] - v;
}

__global__ void scan3_kernel(const int* __restrict__ tmp, const int* __restrict__ boff,
                             int* __restrict__ out, int n) {
    int i = blockIdx.x * blockDim.x + threadIdx.x;
    if (i < n) out[i] = tmp[i] + boff[i >> 10];
}

__global__ __launch_bounds__(1024) void bin_scatter(const int* __restrict__ rows,
                                                    const int* __restrict__ cols,
                                                    const float* __restrict__ vals,
                                                    const int* __restrict__ cntS,
                                                    unsigned int* __restrict__ cc,
                                                    unsigned char* __restrict__ rb,
                                                    int E, int nbuk, int ce) {
    __shared__ int cur[MAXBUK];
    for (int i = threadIdx.x; i < nbuk; i += 1024) cur[i] = cntS[i * gridDim.x + blockIdx.x];
    __syncthreads();
    int s = blockIdx.x * ce, e = s + ce < E ? s + ce : E;
    for (int i = s + (int)threadIdx.x; i < e; i += 1024) {
        int r = rows[i];
        int p = atomicAdd(&cur[r >> BUK_SHIFT], 1);
        cc[p] = ((unsigned)cols[i] << 16) | (unsigned)f2bf(vals[i]);
        rb[p] = (unsigned char)(r & (BUK_ROWS - 1));
    }
}

// per-bucket: natural row order, pad each row to %8 with 0 (col=0,val=0); emit rp; write cc2
__global__ __launch_bounds__(1024) void bucket_pad(const unsigned int* __restrict__ cc,
                                                   const unsigned char* __restrict__ rb,
                                                   const int* __restrict__ cntS,
                                                   unsigned int* __restrict__ cc2,
                                                   int2* __restrict__ rp,
                                                   int E, int nbuk, int nblk, int N) {
    __shared__ int cnt[BUK_ROWS];
    __shared__ int psc[BUK_ROWS];
    __shared__ int cur[BUK_ROWS];
    const int b = blockIdx.x;
    const int tid = threadIdx.x;
    const int base = cntS[b * nblk];
    const int end = (b + 1 < nbuk) ? cntS[(b + 1) * nblk] : E;
    const int sz = end - base;
    if (tid < BUK_ROWS) cnt[tid] = 0;
    __syncthreads();
    for (int i = tid; i < sz; i += 1024) atomicAdd(&cnt[rb[base + i]], 1);
    __syncthreads();
    if (tid < BUK_ROWS) psc[tid] = (cnt[tid] + 7) & ~7;
    __syncthreads();
    for (int off = 1; off < BUK_ROWS; off <<= 1) {
        int t = (tid < BUK_ROWS && tid >= off) ? psc[tid - off] : 0;
        __syncthreads();
        if (tid < BUK_ROWS) psc[tid] += t;
        __syncthreads();
    }
    if (tid < BUK_ROWS) {
        int c = cnt[tid];
        int pc = (c + 7) & ~7;
        int excl = psc[tid] - pc;
        cur[tid] = excl;
        int st = b * CAP2 + excl;
        rp[b * BUK_ROWS + tid] = make_int2(st, st + pc);
        for (int z = c; z < pc; ++z) cc2[(size_t)st + z] = 0u;  // pad slots
    }
    __syncthreads();
    for (int i = tid; i < sz; i += 1024) {
        int p = atomicAdd(&cur[rb[base + i]], 1);
        cc2[(size_t)b * CAP2 + p] = cc[base + i];
    }
}

// GEMM: S8 slabs [4][M][64] fp8 = fp8(A[m][256] @ Bt[n][256]^T), bf16 in, f32 accum.
// Block = 64 rows x 256 cols, 4 waves (wave = one 64-col slab). BK=64, A LDS-staged
// (reg-staging, XOR-swizzled for balanced ds_read_b128 banks, double-buffered,
// load-early/write-late). B frags from global per k-step (L2-hot, reuse across blocks).
// Transposed-operand MFMA: mfma(b,a) -> lane holds 4 consecutive feats -> fp8 dword store.
__global__ __launch_bounds__(256) void gemm_kernel(const unsigned short* __restrict__ A,
                                                   const unsigned short* __restrict__ Bt,
                                                   unsigned char* __restrict__ S8, int M) {
    __shared__ unsigned char lds[2][8192];
    const int tid = threadIdx.x;
    const int lane = tid & 63;
    const int wave = tid >> 6;
    const int m0 = blockIdx.x * 64;
    const int l15 = lane & 15;
    const int q = lane >> 4;
    const int sw = (l15 & 7) << 4;        // read-side XOR (r&7 == l15&7 for all mf)

    // staging decode: thread stages rows r0 = tid/8 and r1 = r0+32, col chunk tid%8
    const int st_r0 = tid >> 3;
    const int st_c = tid & 7;
    const int st_off0 = st_r0 * 128 + ((st_c ^ (st_r0 & 7)) << 4);
    const int st_r1 = st_r0 + 32;
    const int st_off1 = st_r1 * 128 + ((st_c ^ (st_r1 & 7)) << 4);
    int row0 = m0 + st_r0; row0 = row0 < M ? row0 : 0;
    int row1 = m0 + st_r1; row1 = row1 < M ? row1 : 0;
    const unsigned short* s0p = A + (size_t)row0 * 256 + st_c * 8;
    const unsigned short* s1p = A + (size_t)row1 * 256 + st_c * 8;

    const unsigned short* bb = Bt + (size_t)(wave * 64 + l15) * 256 + q * 8;

    f32x4 acc[4][4] = {};

    // prologue: stage kk=0 into buf 0
    uint4 s0 = *reinterpret_cast<const uint4*>(s0p);
    uint4 s1 = *reinterpret_cast<const uint4*>(s1p);
    *reinterpret_cast<uint4*>(&lds[0][st_off0]) = s0;
    *reinterpret_cast<uint4*>(&lds[0][st_off1]) = s1;
    __syncthreads();

#pragma unroll
    for (int it = 0; it < 4; ++it) {
        const int buf = it & 1;
        if (it < 3) {           // issue next-tile loads early
            s0 = *reinterpret_cast<const uint4*>(s0p + (it + 1) * 64);
            s1 = *reinterpret_cast<const uint4*>(s1p + (it + 1) * 64);
        }
        const int kk = it * 64;
#pragma unroll
        for (int ks = 0; ks < 2; ++ks) {
            short8 a[4], b[4];
#pragma unroll
            for (int mf = 0; mf < 4; ++mf) {
                int r = mf * 16 + l15;
                a[mf] = *reinterpret_cast<const short8*>(
                    &lds[buf][r * 128 + ((ks * 64 + q * 16) ^ sw)]);
            }
#pragma unroll
            for (int nf = 0; nf < 4; ++nf)
                b[nf] = *reinterpret_cast<const short8*>(bb + (size_t)nf * 16 * 256 + kk + ks * 32);
#pragma unroll
            for (int mf = 0; mf < 4; ++mf)
#pragma unroll
                for (int nf = 0; nf < 4; ++nf)
                    acc[mf][nf] = __builtin_amdgcn_mfma_f32_16x16x32_bf16(b[nf], a[mf], acc[mf][nf], 0, 0, 0);
        }
        if (it < 3) {           // write-late into the other buffer
            *reinterpret_cast<uint4*>(&lds[buf ^ 1][st_off0]) = s0;
            *reinterpret_cast<uint4*>(&lds[buf ^ 1][st_off1]) = s1;
        }
        __syncthreads();
    }

    const int g4 = q * 4;
#pragma unroll
    for (int mf = 0; mf < 4; ++mf) {
        int m = m0 + mf * 16 + l15;
        if (m < M) {
#pragma unroll
            for (int nf = 0; nf < 4; ++nf) {
                int p = __builtin_amdgcn_cvt_pk_fp8_f32(acc[mf][nf][0], acc[mf][nf][1], 0, false);
                p = __builtin_amdgcn_cvt_pk_fp8_f32(acc[mf][nf][2], acc[mf][nf][3], p, true);
                *reinterpret_cast<int*>(S8 + ((size_t)wave * M + m) * 64 + nf * 16 + g4) = p;
            }
        }
    }
}

// SpMM over one 64-feature slab (blockIdx.y): wave = 4 rows x 16 lanes; lane owns 4 feats
template <int LAYER2>
__global__ __launch_bounds__(256) void spmm_kernel(const unsigned char* __restrict__ S8,
                                                   const int2* __restrict__ rp,
                                                   const unsigned int* __restrict__ cc,
                                                   const float* __restrict__ bias,
                                                   unsigned short* __restrict__ out_bf,
                                                   float* __restrict__ out_f,
                                                   const int* __restrict__ pos_idx, int N) {
    const int slab = blockIdx.y;
    const int lane = threadIdx.x & 63;
    const int wid = threadIdx.x >> 6;
    const int q = lane >> 4;
    const int l = lane & 15;
    const int row = blockIdx.x * 16 + wid * 4 + q;
    const int2 r = rp[row];
    float a0 = 0.f, a1 = 0.f, a2 = 0.f, a3 = 0.f;
    const unsigned char* Sl = S8 + (size_t)slab * N * 64 + l * 4;
    for (int i = r.x; i < r.y; i += 8) {
        uint4 c0 = *reinterpret_cast<const uint4*>(cc + i);
        uint4 c1 = *reinterpret_cast<const uint4*>(cc + i + 4);
        unsigned w0 = *reinterpret_cast<const unsigned*>(Sl + ((size_t)(c0.x >> 16) << 6));
        unsigned w1 = *reinterpret_cast<const unsigned*>(Sl + ((size_t)(c0.y >> 16) << 6));
        unsigned w2 = *reinterpret_cast<const unsigned*>(Sl + ((size_t)(c0.z >> 16) << 6));
        unsigned w3 = *reinterpret_cast<const unsigned*>(Sl + ((size_t)(c0.w >> 16) << 6));
        unsigned w4 = *reinterpret_cast<const unsigned*>(Sl + ((size_t)(c1.x >> 16) << 6));
        unsigned w5 = *reinterpret_cast<const unsigned*>(Sl + ((size_t)(c1.y >> 16) << 6));
        unsigned w6 = *reinterpret_cast<const unsigned*>(Sl + ((size_t)(c1.z >> 16) << 6));
        unsigned w7 = *reinterpret_cast<const unsigned*>(Sl + ((size_t)(c1.w >> 16) << 6));
        float v0 = __uint_as_float(c0.x << 16), v1 = __uint_as_float(c0.y << 16);
        float v2 = __uint_as_float(c0.z << 16), v3 = __uint_as_float(c0.w << 16);
        float v4 = __uint_as_float(c1.x << 16), v5 = __uint_as_float(c1.y << 16);
        float v6 = __uint_as_float(c1.z << 16), v7 = __uint_as_float(c1.w << 16);
#define ACC(ww, vv) { \
        f32x2 plo = __builtin_amdgcn_cvt_pk_f32_fp8((int)ww, false); \
        f32x2 phi = __builtin_amdgcn_cvt_pk_f32_fp8((int)ww, true);  \
        a0 += vv * plo.x; a1 += vv * plo.y; a2 += vv * phi.x; a3 += vv * phi.y; }
        ACC(w0, v0) ACC(w1, v1) ACC(w2, v2) ACC(w3, v3)
        ACC(w4, v4) ACC(w5, v5) ACC(w6, v6) ACC(w7, v7)
#undef ACC
    }
    if (row >= N) return;
    const int f = slab * 64 + l * 4;
    a0 = fmaxf(a0 + bias[f + 0], 0.f);
    a1 = fmaxf(a1 + bias[f + 1], 0.f);
    a2 = fmaxf(a2 + bias[f + 2], 0.f);
    a3 = fmaxf(a3 + bias[f + 3], 0.f);
    if (LAYER2) {
        int orow = pos_idx[row];
        *reinterpret_cast<float4*>(out_f + (size_t)orow * 256 + f) = make_float4(a0, a1, a2, a3);
    } else {
        ushort4 o;
        o.x = f2bf(a0); o.y = f2bf(a1); o.z = f2bf(a2); o.w = f2bf(a3);
        *reinterpret_cast<ushort4*>(out_bf + (size_t)row * 256 + f) = o;
    }
}

extern "C" void kernel_launch(void* const* d_in, const int* in_sizes, int n_in,
                              void* d_out, int out_size, void* d_ws, size_t ws_size,
                              hipStream_t stream) {
    const float* x        = (const float*)d_in[0];
    const int* adj_rows   = (const int*)d_in[1];
    const int* adj_cols   = (const int*)d_in[2];
    const float* adj_vals = (const float*)d_in[3];
    const int* pos_idx    = (const int*)d_in[5];
    const float* W1       = (const float*)d_in[6];
    const float* b1       = (const float*)d_in[7];
    const float* W2       = (const float*)d_in[8];
    const float* b2       = (const float*)d_in[9];

    const int N = in_sizes[0] / 256;
    const int E = in_sizes[1];
    const int nbuk = (N + BUK_ROWS - 1) >> BUK_SHIFT;       // 391
    const int n2 = nbuk * NBLK_BIN;                         // 100096
    const int nb2 = (n2 + 1023) / 1024;                     // 98
    const int ce = (E + NBLK_BIN - 1) / NBLK_BIN;           // 6250
    const int nwork = nbuk * BUK_ROWS;                      // 50048

    char* ws = (char*)d_ws;
    size_t off = 0;
    auto alloc = [&](size_t bytes) {
        char* p = ws + off;
        off += (bytes + 255) & ~(size_t)255;
        return p;
    };
    unsigned short* xb   = (unsigned short*)alloc((size_t)N * 256 * 2); // x bf16, reused as h
    unsigned char*  sup8 = (unsigned char*)alloc((size_t)N * 256);      // fp8 support, slab layout
    unsigned short* w1t  = (unsigned short*)alloc(256 * 256 * 2);
    unsigned short* w2t  = (unsigned short*)alloc(256 * 256 * 2);
    int2* rp     = (int2*)alloc((size_t)nwork * 8);
    int* cntM    = (int*)alloc((size_t)n2 * 4);
    int* cntS    = (int*)alloc((size_t)n2 * 4);
    int* tmp     = (int*)alloc((size_t)n2 * 4);
    int* bsum    = (int*)alloc(512 * 4);
    int* boff    = (int*)alloc(512 * 4);
    unsigned int* cc  = (unsigned int*)alloc((size_t)E * 4);
    unsigned char* rb = (unsigned char*)alloc((size_t)E);
    unsigned int* cc2 = (unsigned int*)alloc((size_t)nbuk * CAP2 * 4);
    (void)ws_size; (void)n_in;

    // only rows [N, PAD_N) need zeroing: spmm layer-2 writes all rows pos_idx[0..N) fully
    hipMemsetAsync((float*)d_out + (size_t)N * 256, 0,
                   ((size_t)out_size - (size_t)N * 256) * 4, stream);

    cvt_kernel<<<(N * 64 + 255) / 256, 256, 0, stream>>>(x, xb, N * 64);
    wtr_kernel<<<256, 256, 0, stream>>>(W1, w1t);
    wtr_kernel<<<256, 256, 0, stream>>>(W2, w2t);

    // CSR build (natural order, padded, 4B packed)
    bin_count<<<NBLK_BIN, 1024, 0, stream>>>(adj_rows, cntM, E, nbuk, ce);
    scan1_kernel<<<nb2, 1024, 0, stream>>>(cntM, tmp, bsum, n2);
    scan2_kernel<<<1, 512, 0, stream>>>(bsum, boff, nb2);
    scan3_kernel<<<(n2 + 255) / 256, 256, 0, stream>>>(tmp, boff, cntS, n2);
    bin_scatter<<<NBLK_BIN, 1024, 0, stream>>>(adj_rows, adj_cols, adj_vals, cntS, cc, rb, E, nbuk, ce);
    bucket_pad<<<nbuk, 1024, 0, stream>>>(cc, rb, cntS, cc2, rp, E, nbuk, NBLK_BIN, N);

    const int ggrid = (N + 63) / 64;
    const dim3 sgrid(nwork / 16, 4);
    // layer 1
    gemm_kernel<<<ggrid, 256, 0, stream>>>(xb, w1t, sup8, N);
    spmm_kernel<0><<<sgrid, 256, 0, stream>>>(sup8, rp, cc2, b1, xb, nullptr, nullptr, N);
    // layer 2
    gemm_kernel<<<ggrid, 256, 0, stream>>>(xb, w2t, sup8, N);
    spmm_kernel<1><<<sgrid, 256, 0, stream>>>(sup8, rp, cc2, b2, nullptr, (float*)d_out, pos_idx, N);
}

// Round 9
// 224.846 us; speedup vs baseline: 1.2540x; 1.0280x over previous
//
#include <hip/hip_runtime.h>
#include <hip/hip_bf16.h>

typedef __attribute__((ext_vector_type(8))) short short8;
typedef __attribute__((ext_vector_type(4))) float f32x4;
typedef __attribute__((ext_vector_type(2))) float f32x2;

#define BUK_SHIFT 7
#define BUK_ROWS 128
#define MAXBUK 400
#define CAP2 6144      // per-bucket stride (4B elems) in padded edge array
#define CHUNK 6250     // edges per bin block
#define CHUNK_PAD 6272

static __device__ __forceinline__ unsigned short f2bf(float f) {
    unsigned u = __float_as_uint(f);
    u += 0x7fffu + ((u >> 16) & 1u);
    return (unsigned short)(u >> 16);
}
static __device__ __forceinline__ unsigned pk2bf(float a, float b) {
    return (unsigned)f2bf(a) | ((unsigned)f2bf(b) << 16);
}

__global__ void wtr_kernel(const float* __restrict__ W, unsigned short* __restrict__ Wt) {
    int k = blockIdx.x, n = threadIdx.x;
    Wt[n * 256 + k] = f2bf(W[k * 256 + n]);
}

// ---- CSR build (two-level binning; natural row order; rows padded to %8; 4B packed edges) ----

__global__ __launch_bounds__(1024) void bin_count(const int* __restrict__ rows,
                                                  int* __restrict__ cntM, int E, int nbuk) {
    __shared__ int c[MAXBUK];
    for (int i = threadIdx.x; i < nbuk; i += 1024) c[i] = 0;
    __syncthreads();
    int s = blockIdx.x * CHUNK, e = s + CHUNK < E ? s + CHUNK : E;
    for (int i = s + (int)threadIdx.x; i < e; i += 1024) atomicAdd(&c[rows[i] >> BUK_SHIFT], 1);
    __syncthreads();
    for (int i = threadIdx.x; i < nbuk; i += 1024) cntM[i * gridDim.x + blockIdx.x] = c[i];
}

__global__ __launch_bounds__(1024) void scan1_kernel(const int* __restrict__ in,
                                                     int* __restrict__ tmp,
                                                     int* __restrict__ bsum, int n) {
    __shared__ int sdata[1024];
    int i = blockIdx.x * 1024 + threadIdx.x;
    int v = (i < n) ? in[i] : 0;
    sdata[threadIdx.x] = v;
    __syncthreads();
    for (int off = 1; off < 1024; off <<= 1) {
        int t = (threadIdx.x >= (unsigned)off) ? sdata[threadIdx.x - off] : 0;
        __syncthreads();
        sdata[threadIdx.x] += t;
        __syncthreads();
    }
    if (i < n) tmp[i] = sdata[threadIdx.x] - v;
    if (threadIdx.x == 1023) bsum[blockIdx.x] = sdata[1023];
}

__global__ __launch_bounds__(512) void scan2_kernel(const int* __restrict__ bsum,
                                                    int* __restrict__ boff, int nb) {
    __shared__ int s[512];
    int t = threadIdx.x;
    int v = (t < nb) ? bsum[t] : 0;
    s[t] = v;
    __syncthreads();
    for (int off = 1; off < 512; off <<= 1) {
        int x = (t >= off) ? s[t - off] : 0;
        __syncthreads();
        s[t] += x;
        __syncthreads();
    }
    if (t < nb) boff[t] = s[t] - v;
}

__global__ void scan3_kernel(const int* __restrict__ tmp, const int* __restrict__ boff,
                             int* __restrict__ out, int n) {
    int i = blockIdx.x * blockDim.x + threadIdx.x;
    if (i < n) out[i] = tmp[i] + boff[i >> 10];
}

// LDS-staged bucket sort of the chunk: coalesced global writes of per-bucket runs
__global__ __launch_bounds__(1024) void bin_scatter(const int* __restrict__ rows,
                                                    const int* __restrict__ cols,
                                                    const float* __restrict__ vals,
                                                    const int* __restrict__ cntS,
                                                    unsigned int* __restrict__ cc,
                                                    unsigned char* __restrict__ rb,
                                                    int E, int nbuk, int nblk) {
    __shared__ unsigned int scc[CHUNK_PAD];
    __shared__ unsigned char srb[CHUNK_PAD];
    __shared__ int lcnt[512], lsc[512], lcur[512];
    const int b = blockIdx.x, tid = threadIdx.x;
    const int s = b * CHUNK, e = s + CHUNK < E ? s + CHUNK : E;
    if (tid < 512) lcnt[tid] = 0;
    __syncthreads();
    for (int i = s + tid; i < e; i += 1024) atomicAdd(&lcnt[rows[i] >> BUK_SHIFT], 1);
    __syncthreads();
    if (tid < 512) lsc[tid] = lcnt[tid];
    __syncthreads();
    for (int off = 1; off < 512; off <<= 1) {
        int t = (tid < 512 && tid >= off) ? lsc[tid - off] : 0;
        __syncthreads();
        if (tid < 512) lsc[tid] += t;
        __syncthreads();
    }
    if (tid < 512) lcur[tid] = lsc[tid] - lcnt[tid];
    __syncthreads();
    for (int i = s + tid; i < e; i += 1024) {
        int r = rows[i];
        int p = atomicAdd(&lcur[r >> BUK_SHIFT], 1);
        scc[p] = ((unsigned)cols[i] << 16) | (unsigned)f2bf(vals[i]);
        srb[p] = (unsigned char)(r & (BUK_ROWS - 1));
    }
    __syncthreads();
    const int wv = tid >> 6, ln = tid & 63;
    for (int bu = wv; bu < nbuk; bu += 16) {
        const int lo = lsc[bu] - lcnt[bu];
        const int n = lcnt[bu];
        const int gbase = cntS[bu * nblk + b];
        for (int j = ln; j < n; j += 64) {
            cc[gbase + j] = scc[lo + j];
            rb[gbase + j] = srb[lo + j];
        }
    }
}

// per-bucket: natural row order, pad each row to %8 with 0 (col=0,val=0); emit rp; write cc2
__global__ __launch_bounds__(1024) void bucket_pad(const unsigned int* __restrict__ cc,
                                                   const unsigned char* __restrict__ rb,
                                                   const int* __restrict__ cntS,
                                                   unsigned int* __restrict__ cc2,
                                                   int2* __restrict__ rp,
                                                   int E, int nbuk, int nblk, int N) {
    __shared__ int cnt[BUK_ROWS];
    __shared__ int psc[BUK_ROWS];
    __shared__ int cur[BUK_ROWS];
    const int b = blockIdx.x;
    const int tid = threadIdx.x;
    const int base = cntS[b * nblk];
    const int end = (b + 1 < nbuk) ? cntS[(b + 1) * nblk] : E;
    const int sz = end - base;
    if (tid < BUK_ROWS) cnt[tid] = 0;
    __syncthreads();
    for (int i = tid; i < sz; i += 1024) atomicAdd(&cnt[rb[base + i]], 1);
    __syncthreads();
    if (tid < BUK_ROWS) psc[tid] = (cnt[tid] + 7) & ~7;
    __syncthreads();
    for (int off = 1; off < BUK_ROWS; off <<= 1) {
        int t = (tid < BUK_ROWS && tid >= off) ? psc[tid - off] : 0;
        __syncthreads();
        if (tid < BUK_ROWS) psc[tid] += t;
        __syncthreads();
    }
    if (tid < BUK_ROWS) {
        int c = cnt[tid];
        int pc = (c + 7) & ~7;
        int excl = psc[tid] - pc;
        cur[tid] = excl;
        int st = b * CAP2 + excl;
        rp[b * BUK_ROWS + tid] = make_int2(st, st + pc);
        for (int z = c; z < pc; ++z) cc2[(size_t)st + z] = 0u;  // pad slots
    }
    __syncthreads();
    for (int i = tid; i < sz; i += 1024) {
        int p = atomicAdd(&cur[rb[base + i]], 1);
        cc2[(size_t)b * CAP2 + p] = cc[base + i];
    }
}

// load a 8-element bf16 fragment for LDS staging; AF32: convert from f32 on the fly
template <int AF32>
static __device__ __forceinline__ uint4 load_frag(const char* p) {
    if (AF32) {
        const float* f = (const float*)p;
        float4 f0 = *reinterpret_cast<const float4*>(f);
        float4 f1 = *reinterpret_cast<const float4*>(f + 4);
        uint4 u;
        u.x = pk2bf(f0.x, f0.y); u.y = pk2bf(f0.z, f0.w);
        u.z = pk2bf(f1.x, f1.y); u.w = pk2bf(f1.z, f1.w);
        return u;
    }
    return *reinterpret_cast<const uint4*>(p);
}

// GEMM: S8 slabs [4][M][64] fp8 = fp8(A[m][256] @ Bt[n][256]^T), f32 accum.
// AF32: A is f32 (layer 1, conversion fused into LDS staging); else bf16.
// Block = 64 rows x 256 cols, 4 waves (wave = one 64-col slab). BK=64, A LDS-staged,
// XOR-swizzled, double-buffered, load-early/write-late. B frags from global (L2-hot).
// Transposed-operand MFMA: mfma(b,a) -> lane holds 4 consecutive feats -> fp8 dword store.
template <int AF32>
__global__ __launch_bounds__(256) void gemm_kernel(const void* __restrict__ Av,
                                                   const unsigned short* __restrict__ Bt,
                                                   unsigned char* __restrict__ S8, int M) {
    __shared__ unsigned char lds[2][8192];
    const int esz = AF32 ? 4 : 2;
    const int tid = threadIdx.x;
    const int lane = tid & 63;
    const int wave = tid >> 6;
    const int m0 = blockIdx.x * 64;
    const int l15 = lane & 15;
    const int q = lane >> 4;
    const int sw = (l15 & 7) << 4;        // read-side XOR (r&7 == l15&7 for all mf)

    const int st_r0 = tid >> 3;
    const int st_c = tid & 7;
    const int st_off0 = st_r0 * 128 + ((st_c ^ (st_r0 & 7)) << 4);
    const int st_r1 = st_r0 + 32;
    const int st_off1 = st_r1 * 128 + ((st_c ^ (st_r1 & 7)) << 4);
    int row0 = m0 + st_r0; row0 = row0 < M ? row0 : 0;
    int row1 = m0 + st_r1; row1 = row1 < M ? row1 : 0;
    const char* s0p = (const char*)Av + ((size_t)row0 * 256 + st_c * 8) * esz;
    const char* s1p = (const char*)Av + ((size_t)row1 * 256 + st_c * 8) * esz;

    const unsigned short* bb = Bt + (size_t)(wave * 64 + l15) * 256 + q * 8;

    f32x4 acc[4][4] = {};

    uint4 s0 = load_frag<AF32>(s0p);
    uint4 s1 = load_frag<AF32>(s1p);
    *reinterpret_cast<uint4*>(&lds[0][st_off0]) = s0;
    *reinterpret_cast<uint4*>(&lds[0][st_off1]) = s1;
    __syncthreads();

#pragma unroll
    for (int it = 0; it < 4; ++it) {
        const int buf = it & 1;
        if (it < 3) {           // issue next-tile loads early
            s0 = load_frag<AF32>(s0p + (size_t)(it + 1) * 64 * esz);
            s1 = load_frag<AF32>(s1p + (size_t)(it + 1) * 64 * esz);
        }
        const int kk = it * 64;
#pragma unroll
        for (int ks = 0; ks < 2; ++ks) {
            short8 a[4], b[4];
#pragma unroll
            for (int mf = 0; mf < 4; ++mf) {
                int r = mf * 16 + l15;
                a[mf] = *reinterpret_cast<const short8*>(
                    &lds[buf][r * 128 + ((ks * 64 + q * 16) ^ sw)]);
            }
#pragma unroll
            for (int nf = 0; nf < 4; ++nf)
                b[nf] = *reinterpret_cast<const short8*>(bb + (size_t)nf * 16 * 256 + kk + ks * 32);
#pragma unroll
            for (int mf = 0; mf < 4; ++mf)
#pragma unroll
                for (int nf = 0; nf < 4; ++nf)
                    acc[mf][nf] = __builtin_amdgcn_mfma_f32_16x16x32_bf16(b[nf], a[mf], acc[mf][nf], 0, 0, 0);
        }
        if (it < 3) {           // write-late into the other buffer
            *reinterpret_cast<uint4*>(&lds[buf ^ 1][st_off0]) = s0;
            *reinterpret_cast<uint4*>(&lds[buf ^ 1][st_off1]) = s1;
        }
        __syncthreads();
    }

    const int g4 = q * 4;
#pragma unroll
    for (int mf = 0; mf < 4; ++mf) {
        int m = m0 + mf * 16 + l15;
        if (m < M) {
#pragma unroll
            for (int nf = 0; nf < 4; ++nf) {
                int p = __builtin_amdgcn_cvt_pk_fp8_f32(acc[mf][nf][0], acc[mf][nf][1], 0, false);
                p = __builtin_amdgcn_cvt_pk_fp8_f32(acc[mf][nf][2], acc[mf][nf][3], p, true);
                *reinterpret_cast<int*>(S8 + ((size_t)wave * M + m) * 64 + nf * 16 + g4) = p;
            }
        }
    }
}

// SpMM over one 64-feature slab (blockIdx.y): wave = 4 rows x 16 lanes; lane owns 4 feats.
// f32x2 accumulators -> v_pk_fma_f32 (2 FMA/instr).
template <int LAYER2>
__global__ __launch_bounds__(256) void spmm_kernel(const unsigned char* __restrict__ S8,
                                                   const int2* __restrict__ rp,
                                                   const unsigned int* __restrict__ cc,
                                                   const float* __restrict__ bias,
                                                   unsigned short* __restrict__ out_bf,
                                                   float* __restrict__ out_f,
                                                   const int* __restrict__ pos_idx, int N) {
    const int slab = blockIdx.y;
    const int lane = threadIdx.x & 63;
    const int wid = threadIdx.x >> 6;
    const int q = lane >> 4;
    const int l = lane & 15;
    const int row = blockIdx.x * 16 + wid * 4 + q;
    const int2 r = rp[row];
    f32x2 a01 = {0.f, 0.f}, a23 = {0.f, 0.f};
    const unsigned char* Sl = S8 + (size_t)slab * N * 64 + l * 4;
    for (int i = r.x; i < r.y; i += 8) {
        uint4 c0 = *reinterpret_cast<const uint4*>(cc + i);
        uint4 c1 = *reinterpret_cast<const uint4*>(cc + i + 4);
        unsigned w0 = *reinterpret_cast<const unsigned*>(Sl + ((size_t)(c0.x >> 16) << 6));
        unsigned w1 = *reinterpret_cast<const unsigned*>(Sl + ((size_t)(c0.y >> 16) << 6));
        unsigned w2 = *reinterpret_cast<const unsigned*>(Sl + ((size_t)(c0.z >> 16) << 6));
        unsigned w3 = *reinterpret_cast<const unsigned*>(Sl + ((size_t)(c0.w >> 16) << 6));
        unsigned w4 = *reinterpret_cast<const unsigned*>(Sl + ((size_t)(c1.x >> 16) << 6));
        unsigned w5 = *reinterpret_cast<const unsigned*>(Sl + ((size_t)(c1.y >> 16) << 6));
        unsigned w6 = *reinterpret_cast<const unsigned*>(Sl + ((size_t)(c1.z >> 16) << 6));
        unsigned w7 = *reinterpret_cast<const unsigned*>(Sl + ((size_t)(c1.w >> 16) << 6));
        float v0 = __uint_as_float(c0.x << 16), v1 = __uint_as_float(c0.y << 16);
        float v2 = __uint_as_float(c0.z << 16), v3 = __uint_as_float(c0.w << 16);
        float v4 = __uint_as_float(c1.x << 16), v5 = __uint_as_float(c1.y << 16);
        float v6 = __uint_as_float(c1.z << 16), v7 = __uint_as_float(c1.w << 16);
#define ACC(ww, vv) { \
        f32x2 plo = __builtin_amdgcn_cvt_pk_f32_fp8((int)ww, false); \
        f32x2 phi = __builtin_amdgcn_cvt_pk_f32_fp8((int)ww, true);  \
        f32x2 vv2 = {vv, vv}; \
        a01 += vv2 * plo; a23 += vv2 * phi; }
        ACC(w0, v0) ACC(w1, v1) ACC(w2, v2) ACC(w3, v3)
        ACC(w4, v4) ACC(w5, v5) ACC(w6, v6) ACC(w7, v7)
#undef ACC
    }
    if (row >= N) return;
    const int f = slab * 64 + l * 4;
    float a0 = fmaxf(a01.x + bias[f + 0], 0.f);
    float a1 = fmaxf(a01.y + bias[f + 1], 0.f);
    float a2 = fmaxf(a23.x + bias[f + 2], 0.f);
    float a3 = fmaxf(a23.y + bias[f + 3], 0.f);
    if (LAYER2) {
        int orow = pos_idx[row];
        *reinterpret_cast<float4*>(out_f + (size_t)orow * 256 + f) = make_float4(a0, a1, a2, a3);
    } else {
        ushort4 o;
        o.x = f2bf(a0); o.y = f2bf(a1); o.z = f2bf(a2); o.w = f2bf(a3);
        *reinterpret_cast<ushort4*>(out_bf + (size_t)row * 256 + f) = o;
    }
}

extern "C" void kernel_launch(void* const* d_in, const int* in_sizes, int n_in,
                              void* d_out, int out_size, void* d_ws, size_t ws_size,
                              hipStream_t stream) {
    const float* x        = (const float*)d_in[0];
    const int* adj_rows   = (const int*)d_in[1];
    const int* adj_cols   = (const int*)d_in[2];
    const float* adj_vals = (const float*)d_in[3];
    const int* pos_idx    = (const int*)d_in[5];
    const float* W1       = (const float*)d_in[6];
    const float* b1       = (const float*)d_in[7];
    const float* W2       = (const float*)d_in[8];
    const float* b2       = (const float*)d_in[9];

    const int N = in_sizes[0] / 256;
    const int E = in_sizes[1];
    const int nbuk = (N + BUK_ROWS - 1) >> BUK_SHIFT;       // 391
    const int nblk = (E + CHUNK - 1) / CHUNK;               // 256
    const int n2 = nbuk * nblk;                             // 100096
    const int nb2 = (n2 + 1023) / 1024;                     // 98
    const int nwork = nbuk * BUK_ROWS;                      // 50048

    char* ws = (char*)d_ws;
    size_t off = 0;
    auto alloc = [&](size_t bytes) {
        char* p = ws + off;
        off += (bytes + 255) & ~(size_t)255;
        return p;
    };
    unsigned short* xb   = (unsigned short*)alloc((size_t)N * 256 * 2); // h (bf16) after layer 1
    unsigned char*  sup8 = (unsigned char*)alloc((size_t)N * 256);      // fp8 support, slab layout
    unsigned short* w1t  = (unsigned short*)alloc(256 * 256 * 2);
    unsigned short* w2t  = (unsigned short*)alloc(256 * 256 * 2);
    int2* rp     = (int2*)alloc((size_t)nwork * 8);
    int* cntM    = (int*)alloc((size_t)n2 * 4);
    int* cntS    = (int*)alloc((size_t)n2 * 4);
    int* tmp     = (int*)alloc((size_t)n2 * 4);
    int* bsum    = (int*)alloc(512 * 4);
    int* boff    = (int*)alloc(512 * 4);
    unsigned int* cc  = (unsigned int*)alloc((size_t)E * 4);
    unsigned char* rb = (unsigned char*)alloc((size_t)E);
    unsigned int* cc2 = (unsigned int*)alloc((size_t)nbuk * CAP2 * 4);
    (void)ws_size; (void)n_in;

    // only rows [N, PAD_N) need zeroing: spmm layer-2 writes all rows pos_idx[0..N) fully
    hipMemsetAsync((float*)d_out + (size_t)N * 256, 0,
                   ((size_t)out_size - (size_t)N * 256) * 4, stream);

    wtr_kernel<<<256, 256, 0, stream>>>(W1, w1t);
    wtr_kernel<<<256, 256, 0, stream>>>(W2, w2t);

    // CSR build (natural order, padded, 4B packed)
    bin_count<<<nblk, 1024, 0, stream>>>(adj_rows, cntM, E, nbuk);
    scan1_kernel<<<nb2, 1024, 0, stream>>>(cntM, tmp, bsum, n2);
    scan2_kernel<<<1, 512, 0, stream>>>(bsum, boff, nb2);
    scan3_kernel<<<(n2 + 255) / 256, 256, 0, stream>>>(tmp, boff, cntS, n2);
    bin_scatter<<<nblk, 1024, 0, stream>>>(adj_rows, adj_cols, adj_vals, cntS, cc, rb, E, nbuk, nblk);
    bucket_pad<<<nbuk, 1024, 0, stream>>>(cc, rb, cntS, cc2, rp, E, nbuk, nblk, N);

    const int ggrid = (N + 63) / 64;
    const dim3 sgrid(nwork / 16, 4);
    // layer 1 (A = x in f32, conversion fused into staging)
    gemm_kernel<1><<<ggrid, 256, 0, stream>>>(x, w1t, sup8, N);
    spmm_kernel<0><<<sgrid, 256, 0, stream>>>(sup8, rp, cc2, b1, xb, nullptr, nullptr, N);
    // layer 2 (A = h in bf16)
    gemm_kernel<0><<<ggrid, 256, 0, stream>>>(xb, w2t, sup8, N);
    spmm_kernel<1><<<sgrid, 256, 0, stream>>>(sup8, rp, cc2, b2, nullptr, (float*)d_out, pos_idx, N);
}